// Round 12
// baseline (373.026 us; speedup 1.0000x reference)
//
#include <hip/hip_runtime.h>
#include <math.h>

// FactorizationMachine: out = sigmoid( X@fc_w + fc_b + 0.5*( sum_d (X@w)_d^2 - (X^2)@g ) )
//
// R11 theory: all ~290us variants (R0/R4/R9/R10) share 2 waves/SIMD — a wave's
// ~2000cy HBM stall is covered by only ONE other wave's ~600cy compute window
// -> ~60% exposed latency (165us byte-floor -> 283us observed). R8's 16-wave
// attempt failed only because VGPR=64 killed hoisting. Fix: 4 rows/wave so the
// hoisted schedule fits 128 VGPR: 68 acc + 16 xv + 16 wtb + 8 fw/gn + addr ~123.
//  - 256 thr = 4 waves x 4 rows = 16 rows/block; KSPLIT=2 -> 512 blocks = 2/CU;
//    __launch_bounds__(256,4) -> 16 waves/CU (4/SIMD).
//  - wT[d][f] + gneg[f] from phase 0 (validated); wT in 4 batches of 4 regs.
//  - chunk parity -> XCD parity: wT hot set 1.6 MB/L2.
//  - Phase 2 combines KSPLIT=2 partials + sigmoid (validated).

constexpr int B_ROWS  = 4096;
constexpr int F_FEAT  = 50000;
constexpr int NF4     = F_FEAT / 4;        // 12500
constexpr int D_FAC   = 16;
constexpr int TPB     = 256;
constexpr int WPB     = 4;                 // waves per block
constexpr int ROWS    = 4;                 // rows per wave
constexpr int RB      = WPB * ROWS;        // 16 rows per block
constexpr int NGRP    = B_ROWS / RB;       // 256 row-groups
constexpr int KSPLIT  = 2;
constexpr int CHUNK   = NF4 / KSPLIT;      // 6250
constexpr int NBLK    = NGRP * KSPLIT;     // 512 blocks (2 per CU)
constexpr int NVAL    = ROWS * (D_FAC + 1);// 68 partials per wave

constexpr size_t WT_OFF = 0;                       // wT: 16 * 50000 floats
constexpr size_t G_OFF  = (size_t)D_FAC * F_FEAT;  // gneg: 50000
constexpr size_t P_OFF  = G_OFF + F_FEAT;          // partials

typedef float f32x4 __attribute__((ext_vector_type(4)));

// ---------------- Phase 0: W transpose + gneg (validated) ----------------
__global__ __launch_bounds__(256)
void fm_prep(const float* __restrict__ W, float* __restrict__ ws)
{
    const int f = blockIdx.x * 256 + threadIdx.x;
    if (f >= F_FEAT) return;
    const f32x4* W4 = reinterpret_cast<const f32x4*>(W);
    f32x4 wv[4];
#pragma unroll
    for (int q = 0; q < 4; ++q) wv[q] = W4[(size_t)f * 4 + q];
    float gs = 0.f;
#pragma unroll
    for (int t = 0; t < D_FAC; ++t) {
        const float wd = wv[t >> 2][t & 3];
        gs = fmaf(wd, wd, gs);
        ws[WT_OFF + (size_t)t * F_FEAT + f] = wd;
    }
    ws[G_OFF + f] = -0.5f * gs;
}

// ---------------- Phase 1: main sweep ----------------
__global__ __launch_bounds__(TPB, 4)   // 4 waves/EU -> 16 waves/CU; VGPR cap 128
void fm_main(const float* __restrict__ X,
             const float* __restrict__ fcw,
             const float* __restrict__ wt,     // ws + WT_OFF
             const float* __restrict__ gneg,   // ws + G_OFF
             float* __restrict__ pout)         // ws + P_OFF
{
    const int tid  = threadIdx.x;
    const int lane = tid & 63;
    const int wid  = tid >> 6;             // 0..3, wave-uniform
    const int c    = blockIdx.x & (KSPLIT - 1);
    const int grp  = blockIdx.x >> 1;
    const int row0 = grp * RB + wid * ROWS;
    const int beg  = c * CHUNK;
    const int end  = beg + CHUNK;

    const f32x4* X4  = reinterpret_cast<const f32x4*>(X);
    const f32x4* WT4 = reinterpret_cast<const f32x4*>(wt);
    const f32x4* FW4 = reinterpret_cast<const f32x4*>(fcw);
    const f32x4* G4  = reinterpret_cast<const f32x4*>(gneg);

    float s[ROWS][D_FAC];                  // 64 acc
    float lin[ROWS];                       // 4
#pragma unroll
    for (int r = 0; r < ROWS; ++r) {
        lin[r] = 0.f;
#pragma unroll
        for (int t = 0; t < D_FAC; ++t) s[r][t] = 0.f;
    }

    for (int f4 = beg + lane; f4 < end; f4 += 64) {
        // 4 coalesced X streams, hoisted first (the HBM-critical loads)
        f32x4 xv[ROWS];
#pragma unroll
        for (int r = 0; r < ROWS; ++r)
            xv[r] = X4[(size_t)(row0 + r) * NF4 + f4];

        const f32x4 fw = FW4[f4];
        const f32x4 gn = G4[f4];

        // wT in 4 batches of 4 coalesced streams (16 regs re-used per batch)
#pragma unroll
        for (int b = 0; b < 4; ++b) {
            f32x4 wtb[4];
#pragma unroll
            for (int k = 0; k < 4; ++k)
                wtb[k] = WT4[(size_t)(4 * b + k) * NF4 + f4];

#pragma unroll
            for (int j = 0; j < 4; ++j) {
#pragma unroll
                for (int r = 0; r < ROWS; ++r) {
                    const float x = xv[r][j];
#pragma unroll
                    for (int k = 0; k < 4; ++k)
                        s[r][4 * b + k] = fmaf(x, wtb[k][j], s[r][4 * b + k]);
                }
            }
        }

        // linear + sum_sq-correction (fused)
#pragma unroll
        for (int j = 0; j < 4; ++j) {
            const float fwj = fw[j];
            const float gnj = gn[j];
#pragma unroll
            for (int r = 0; r < ROWS; ++r) {
                const float x = xv[r][j];
                lin[r] = fmaf(x, fwj, lin[r]);
                lin[r] = fmaf(x * x, gnj, lin[r]);
            }
        }
    }

    // ---- per-wave butterfly reduce of 68 values; value i -> lane i&63 ----
    float keep0 = 0.f, keep1 = 0.f;
    int idx = 0;
#pragma unroll
    for (int r = 0; r < ROWS; ++r) {
#pragma unroll
        for (int t = 0; t <= D_FAC; ++t) {
            float v = (t < D_FAC) ? s[r][t] : lin[r];
#pragma unroll
            for (int m = 32; m >= 1; m >>= 1) v += __shfl_xor(v, m, 64);
            if (idx < 64) { if (lane == idx)      keep0 = v; }
            else          { if (lane == idx - 64) keep1 = v; }
            ++idx;
        }
    }
    float* base = pout + ((size_t)blockIdx.x * WPB + wid) * NVAL;
    base[lane] = keep0;
    if (lane < NVAL - 64) base[64 + lane] = keep1;
}

// ---------------- Phase 2: combine chunks + sigmoid ----------------
__global__ __launch_bounds__(256)
void fm_final(const float* __restrict__ pout,
              const float* __restrict__ fcb,
              float* __restrict__ out)
{
    const int r = blockIdx.x * 256 + threadIdx.x;
    if (r >= B_ROWS) return;
    const int grp = r >> 4;                // row-group of 16
    const int rr  = r & 15;
    const int wid = rr >> 2;               // wave within block
    const int rw  = rr & 3;                // row within wave

    float acc[D_FAC + 1];
#pragma unroll
    for (int t = 0; t <= D_FAC; ++t) acc[t] = 0.f;

#pragma unroll
    for (int c = 0; c < KSPLIT; ++c) {
        const float* p = pout
            + ((size_t)((grp * KSPLIT + c) * WPB + wid)) * NVAL + rw * (D_FAC + 1);
#pragma unroll
        for (int t = 0; t <= D_FAC; ++t) acc[t] += p[t];
    }

    float ss = 0.f;
#pragma unroll
    for (int t = 0; t < D_FAC; ++t) ss = fmaf(acc[t], acc[t], ss);

    const float logit = acc[D_FAC] + fcb[0] + 0.5f * ss;
    out[r] = 1.0f / (1.0f + expf(-logit));
}

extern "C" void kernel_launch(void* const* d_in, const int* in_sizes, int n_in,
                              void* d_out, int out_size, void* d_ws, size_t ws_size,
                              hipStream_t stream)
{
    const float* X   = (const float*)d_in[0];
    const float* fcw = (const float*)d_in[1];
    const float* fcb = (const float*)d_in[2];
    const float* W   = (const float*)d_in[3];
    float* out = (float*)d_out;
    float* ws  = (float*)d_ws;   // ~4 MB used

    hipLaunchKernelGGL(fm_prep, dim3((F_FEAT + 255) / 256), dim3(256), 0, stream,
                       W, ws);
    hipLaunchKernelGGL(fm_main, dim3(NBLK), dim3(TPB), 0, stream,
                       X, fcw, ws + WT_OFF, ws + G_OFF, ws + P_OFF);
    hipLaunchKernelGGL(fm_final, dim3((B_ROWS + 255) / 256), dim3(256), 0, stream,
                       ws + P_OFF, fcb, out);
}

// Round 13
// 359.660 us; speedup vs baseline: 1.0372x; 1.0372x over previous
//
#include <hip/hip_runtime.h>
#include <math.h>

// FactorizationMachine: out = sigmoid( X@fc_w + fc_b + 0.5*( sum_d (X@w)_d^2 - (X^2)@g ) )
//
// R12: R11's postmortem found a LAUNCH-GEOMETRY bug, not a theory failure:
// 512 blocks over 256 CUs = 2 blocks/CU -> still 8 waves/CU; the 16-waves/CU
// exposed-latency hypothesis was never tested (all R11 did was double wT
// overhead). R12 = same per-wave structure, KSPLIT=4 -> 1024 blocks = TRUE
// 4 blocks/CU x 4 waves = 16 waves/CU (4/SIMD).
//   - per-wave: 4 rows, 68 acc + 16 xv + 16 wtb + 8 fw/gn ~ 124 VGPR <= 128.
//   - wT[d][f] + gneg[f] via phase 0 (validated); chunk c = bid&3 -> XCD
//     pinning, wT hot set 800 KB/L2.
//   - Phase 2 combines KSPLIT=4 partials + sigmoid (validated).
// Discriminator: H1 (latency-starved) -> ~160-210 us. H2 (read-path ceiling
// ~3.15 TB/s) -> ~280-310 us, in which case ~290 us IS the roofline.

constexpr int B_ROWS  = 4096;
constexpr int F_FEAT  = 50000;
constexpr int NF4     = F_FEAT / 4;        // 12500
constexpr int D_FAC   = 16;
constexpr int TPB     = 256;
constexpr int WPB     = 4;                 // waves per block
constexpr int ROWS    = 4;                 // rows per wave
constexpr int RB      = WPB * ROWS;        // 16 rows per block
constexpr int NGRP    = B_ROWS / RB;       // 256 row-groups
constexpr int KSPLIT  = 4;
constexpr int CHUNK   = NF4 / KSPLIT;      // 3125
constexpr int NBLK    = NGRP * KSPLIT;     // 1024 blocks = 4 per CU
constexpr int NVAL    = ROWS * (D_FAC + 1);// 68 partials per wave

constexpr size_t WT_OFF = 0;                       // wT: 16 * 50000 floats
constexpr size_t G_OFF  = (size_t)D_FAC * F_FEAT;  // gneg: 50000
constexpr size_t P_OFF  = G_OFF + F_FEAT;          // partials

typedef float f32x4 __attribute__((ext_vector_type(4)));

// ---------------- Phase 0: W transpose + gneg (validated) ----------------
__global__ __launch_bounds__(256)
void fm_prep(const float* __restrict__ W, float* __restrict__ ws)
{
    const int f = blockIdx.x * 256 + threadIdx.x;
    if (f >= F_FEAT) return;
    const f32x4* W4 = reinterpret_cast<const f32x4*>(W);
    f32x4 wv[4];
#pragma unroll
    for (int q = 0; q < 4; ++q) wv[q] = W4[(size_t)f * 4 + q];
    float gs = 0.f;
#pragma unroll
    for (int t = 0; t < D_FAC; ++t) {
        const float wd = wv[t >> 2][t & 3];
        gs = fmaf(wd, wd, gs);
        ws[WT_OFF + (size_t)t * F_FEAT + f] = wd;
    }
    ws[G_OFF + f] = -0.5f * gs;
}

// ---------------- Phase 1: main sweep ----------------
__global__ __launch_bounds__(TPB, 4)   // 4 waves/EU -> 4 blocks/CU; VGPR cap 128
void fm_main(const float* __restrict__ X,
             const float* __restrict__ fcw,
             const float* __restrict__ wt,     // ws + WT_OFF
             const float* __restrict__ gneg,   // ws + G_OFF
             float* __restrict__ pout)         // ws + P_OFF
{
    const int tid  = threadIdx.x;
    const int lane = tid & 63;
    const int wid  = tid >> 6;             // 0..3, wave-uniform
    const int c    = blockIdx.x & (KSPLIT - 1);
    const int grp  = blockIdx.x >> 2;
    const int row0 = grp * RB + wid * ROWS;
    const int beg  = c * CHUNK;
    const int end  = beg + CHUNK;

    const f32x4* X4  = reinterpret_cast<const f32x4*>(X);
    const f32x4* WT4 = reinterpret_cast<const f32x4*>(wt);
    const f32x4* FW4 = reinterpret_cast<const f32x4*>(fcw);
    const f32x4* G4  = reinterpret_cast<const f32x4*>(gneg);

    float s[ROWS][D_FAC];                  // 64 acc
    float lin[ROWS];                       // 4
#pragma unroll
    for (int r = 0; r < ROWS; ++r) {
        lin[r] = 0.f;
#pragma unroll
        for (int t = 0; t < D_FAC; ++t) s[r][t] = 0.f;
    }

    for (int f4 = beg + lane; f4 < end; f4 += 64) {
        // 4 coalesced X streams, hoisted first (the HBM-critical loads)
        f32x4 xv[ROWS];
#pragma unroll
        for (int r = 0; r < ROWS; ++r)
            xv[r] = X4[(size_t)(row0 + r) * NF4 + f4];

        const f32x4 fw = FW4[f4];
        const f32x4 gn = G4[f4];

        // wT in 4 batches of 4 coalesced streams (16 regs re-used per batch)
#pragma unroll
        for (int b = 0; b < 4; ++b) {
            f32x4 wtb[4];
#pragma unroll
            for (int k = 0; k < 4; ++k)
                wtb[k] = WT4[(size_t)(4 * b + k) * NF4 + f4];

#pragma unroll
            for (int j = 0; j < 4; ++j) {
#pragma unroll
                for (int r = 0; r < ROWS; ++r) {
                    const float x = xv[r][j];
#pragma unroll
                    for (int k = 0; k < 4; ++k)
                        s[r][4 * b + k] = fmaf(x, wtb[k][j], s[r][4 * b + k]);
                }
            }
        }

        // linear + sum_sq-correction (fused)
#pragma unroll
        for (int j = 0; j < 4; ++j) {
            const float fwj = fw[j];
            const float gnj = gn[j];
#pragma unroll
            for (int r = 0; r < ROWS; ++r) {
                const float x = xv[r][j];
                lin[r] = fmaf(x, fwj, lin[r]);
                lin[r] = fmaf(x * x, gnj, lin[r]);
            }
        }
    }

    // ---- per-wave butterfly reduce of 68 values; value i -> lane i&63 ----
    float keep0 = 0.f, keep1 = 0.f;
    int idx = 0;
#pragma unroll
    for (int r = 0; r < ROWS; ++r) {
#pragma unroll
        for (int t = 0; t <= D_FAC; ++t) {
            float v = (t < D_FAC) ? s[r][t] : lin[r];
#pragma unroll
            for (int m = 32; m >= 1; m >>= 1) v += __shfl_xor(v, m, 64);
            if (idx < 64) { if (lane == idx)      keep0 = v; }
            else          { if (lane == idx - 64) keep1 = v; }
            ++idx;
        }
    }
    float* base = pout + ((size_t)blockIdx.x * WPB + wid) * NVAL;
    base[lane] = keep0;
    if (lane < NVAL - 64) base[64 + lane] = keep1;
}

// ---------------- Phase 2: combine chunks + sigmoid ----------------
__global__ __launch_bounds__(256)
void fm_final(const float* __restrict__ pout,
              const float* __restrict__ fcb,
              float* __restrict__ out)
{
    const int r = blockIdx.x * 256 + threadIdx.x;
    if (r >= B_ROWS) return;
    const int grp = r >> 4;                // row-group of 16
    const int rr  = r & 15;
    const int wid = rr >> 2;               // wave within block
    const int rw  = rr & 3;                // row within wave

    float acc[D_FAC + 1];
#pragma unroll
    for (int t = 0; t <= D_FAC; ++t) acc[t] = 0.f;

#pragma unroll
    for (int c = 0; c < KSPLIT; ++c) {
        const float* p = pout
            + ((size_t)((grp * KSPLIT + c) * WPB + wid)) * NVAL + rw * (D_FAC + 1);
#pragma unroll
        for (int t = 0; t <= D_FAC; ++t) acc[t] += p[t];
    }

    float ss = 0.f;
#pragma unroll
    for (int t = 0; t < D_FAC; ++t) ss = fmaf(acc[t], acc[t], ss);

    const float logit = acc[D_FAC] + fcb[0] + 0.5f * ss;
    out[r] = 1.0f / (1.0f + expf(-logit));
}

extern "C" void kernel_launch(void* const* d_in, const int* in_sizes, int n_in,
                              void* d_out, int out_size, void* d_ws, size_t ws_size,
                              hipStream_t stream)
{
    const float* X   = (const float*)d_in[0];
    const float* fcw = (const float*)d_in[1];
    const float* fcb = (const float*)d_in[2];
    const float* W   = (const float*)d_in[3];
    float* out = (float*)d_out;
    float* ws  = (float*)d_ws;   // ~4.5 MB used

    hipLaunchKernelGGL(fm_prep, dim3((F_FEAT + 255) / 256), dim3(256), 0, stream,
                       W, ws);
    hipLaunchKernelGGL(fm_main, dim3(NBLK), dim3(TPB), 0, stream,
                       X, fcw, ws + WT_OFF, ws + G_OFF, ws + P_OFF);
    hipLaunchKernelGGL(fm_final, dim3((B_ROWS + 255) / 256), dim3(256), 0, stream,
                       ws + P_OFF, fcb, out);
}